// Round 6
// baseline (370.070 us; speedup 1.0000x reference)
//
#include <hip/hip_runtime.h>
#include <float.h>

#define K_CLUST 10000
#define K_PAD   10240           // 640 k-tiles of 16
#define DIM     128
#define N_SAMP  16384
#define KSPLIT  16
#define KT_PER  40              // 640 ktiles / 16 splits
#define CAP     16              // candidate list capacity per sample
#define MARGIN2 1.5f            // 2x worst-case f16 score error (~0.38) each side

typedef _Float16 half8  __attribute__((ext_vector_type(8)));
typedef float    floatx4 __attribute__((ext_vector_type(4)));

// order-preserving float<->uint encoding for atomicMax
__device__ inline unsigned enc_f(float f) {
    unsigned u = __float_as_uint(f);
    return u ^ (((int)u >> 31) | 0x80000000u);
}
__device__ inline float dec_f(unsigned u) {
    unsigned t = (u & 0x80000000u) ? (u ^ 0x80000000u) : ~u;
    return __uint_as_float(t);
}

// ---- Kernel 1: prep. blocks [0,160): m-side (msq, mT, mh). [160,416): x-side (xh, inits).
// mh stores (-2 * m) in f16, so the score MFMA computes msq + x·(-2m) directly with
// msq folded into the accumulator init (no fmaf epilogue in the score loop).
__global__ __launch_bounds__(256) void prep_kernel(
        const float* __restrict__ m, const float* __restrict__ x,
        float* __restrict__ msq, float* __restrict__ mT,
        _Float16* __restrict__ mh, _Float16* __restrict__ xh,
        unsigned* __restrict__ smax, int* __restrict__ cnt,
        unsigned* __restrict__ sync, float* __restrict__ diff_out) {
    __shared__ float tile[64][DIM + 1];
    __shared__ float psum[64][4];
    const int b = blockIdx.x, tid = threadIdx.x;

    if (b < 160) {                              // ---- m part: k0 = b*64
        const int k0 = b * 64;
        const int kl = tid & 63, dg = tid >> 6;
        const int k = k0 + kl;
        float ss = 0.f;
        #pragma unroll 4
        for (int dd = 0; dd < 32; ++dd) {
            int d = dg * 32 + dd;
            float v = (k < K_CLUST) ? m[(size_t)d * K_CLUST + k] : 0.f;
            tile[kl][d] = v;
            ss = fmaf(v, v, ss);
        }
        psum[kl][dg] = ss;
        __syncthreads();
        if (dg == 0)
            msq[k] = (k < K_CLUST) ? (psum[kl][0] + psum[kl][1] + psum[kl][2] + psum[kl][3])
                                   : -1e30f;    // pad never wins
        // mh: [k/16][d/8][k%16][d%8] f16, 16B chunks, scaled by -2
        #pragma unroll
        for (int p = 0; p < 4; ++p) {
            int c = tid + p * 256;              // 0..1023
            int kt = c >> 8, dgc = (c >> 4) & 15, k16 = c & 15;
            half8 hv;
            #pragma unroll
            for (int j = 0; j < 8; ++j)
                hv[j] = (_Float16)(-2.0f * tile[kt * 16 + k16][dgc * 8 + j]);
            size_t ci = ((size_t)(b * 4 + kt) * 16 + dgc) * 16 + k16;
            ((half8*)mh)[ci] = hv;
        }
        // mT [K,DIM] fp32 for rescue/quant gather (unscaled)
        const int r = tid >> 2, p2 = tid & 3;
        if (k0 + r < K_CLUST) {
            float4* dst = (float4*)(mT + (size_t)(k0 + r) * DIM + p2 * 32);
            #pragma unroll
            for (int j = 0; j < 8; ++j) {
                float4 v;
                v.x = tile[r][p2 * 32 + 4 * j + 0];
                v.y = tile[r][p2 * 32 + 4 * j + 1];
                v.z = tile[r][p2 * 32 + 4 * j + 2];
                v.w = tile[r][p2 * 32 + 4 * j + 3];
                dst[j] = v;
            }
        }
    } else {                                    // ---- x part: s0 = (b-160)*64
        const int s0 = (b - 160) * 64;
        const float4* xg = (const float4*)(x + (size_t)s0 * DIM);
        #pragma unroll
        for (int i = 0; i < 8; ++i) {
            int fi = tid + i * 256;             // 0..2047
            int sl = fi >> 5, d4 = fi & 31;
            float4 v = xg[fi];
            tile[sl][d4 * 4 + 0] = v.x; tile[sl][d4 * 4 + 1] = v.y;
            tile[sl][d4 * 4 + 2] = v.z; tile[sl][d4 * 4 + 3] = v.w;
        }
        __syncthreads();
        // xh: [s/16][d/8][s%16][d%8]
        #pragma unroll
        for (int p = 0; p < 4; ++p) {
            int c = tid + p * 256;
            int st = c >> 8, dgc = (c >> 4) & 15, ml = c & 15;
            half8 hv;
            #pragma unroll
            for (int j = 0; j < 8; ++j) hv[j] = (_Float16)tile[st * 16 + ml][dgc * 8 + j];
            size_t ci = ((size_t)(s0 / 16 + st) * 16 + dgc) * 16 + ml;
            ((half8*)xh)[ci] = hv;
        }
        if (tid < 64) { smax[s0 + tid] = 0u; cnt[s0 + tid] = 0; }
        if (b == 160) {
            if (tid < 2) sync[tid] = 0u;
            if (tid == 0) *diff_out = 0.f;
        }
    }
}

// ---- Kernel 2: fused max + build + collect (ticket-tail pattern).
// Phase 1 (all 1024 blocks): f16 MFMA max GEMM over this block's (sample-group, split);
//   per-sample global max via atomicMax, split-local max to lmax. Then fence + ticket.
// Tickets [G-16, G): builders — block per split, ballot-compact the worklist of samples
//   with lmax >= global_max - MARGIN2 (spin until all tickets issued => smax complete).
// Tickets [G-272, G-16): collectors — 16 blocks x 4 waves per split; spin until the 16
//   builders are done, then gathered-collect candidates with score >= max - MARGIN2.
// Deadlock-free: every ticket is taken AFTER the block's own work; spinning blocks only
// wait on blocks that have already ticketed (i.e. are resident and past all barriers).
__global__ __launch_bounds__(256, 4) void mbc_kernel(
        const _Float16* __restrict__ xh, const _Float16* __restrict__ mh,
        const float* __restrict__ msq, unsigned* __restrict__ smax,
        float* __restrict__ lmax, int* __restrict__ scnt,
        int* __restrict__ slist, int* __restrict__ cnt,
        int* __restrict__ cand, unsigned* __restrict__ sync) {
    const int tid = threadIdx.x;
    const int wv = tid >> 6, lane = tid & 63;
    const int n = lane & 15, quad = lane >> 4;
    const half8* xf = (const half8*)xh;
    const half8* mf = (const half8*)mh;

    // ================= phase 1: max GEMM =================
    {
        const int ks = blockIdx.x & (KSPLIT - 1);
        const int grp = blockIdx.x / KSPLIT;        // [0,64)
        const int stile0 = (grp * 4 + wv) * 4;      // 4 sample-tiles per wave
        const int kt0 = ks * KT_PER;

        half8 a[4][4];
        #pragma unroll
        for (int ii = 0; ii < 4; ++ii)
            #pragma unroll
            for (int t = 0; t < 4; ++t)
                a[ii][t] = xf[((size_t)(stile0 + ii) * 16 + t * 4 + quad) * 16 + n];

        float rmax[4][4];
        #pragma unroll
        for (int ii = 0; ii < 4; ++ii)
            #pragma unroll
            for (int r = 0; r < 4; ++r) rmax[ii][r] = -FLT_MAX;

        const half8* bp = mf + (size_t)kt0 * 256 + (quad * 16 + n);
        const float* mqp = msq + kt0 * 16 + n;

        #pragma unroll 1
        for (int kt = 0; kt < KT_PER; ++kt) {
            half8 bfr[4];
            #pragma unroll
            for (int t = 0; t < 4; ++t) bfr[t] = bp[t * 64];
            float mq = *mqp;

            floatx4 c[4];
            #pragma unroll
            for (int ii = 0; ii < 4; ++ii)
                c[ii] = (floatx4){mq, mq, mq, mq};   // msq folded: col = lane&15 = k-col
            #pragma unroll
            for (int t = 0; t < 4; ++t)
                #pragma unroll
                for (int ii = 0; ii < 4; ++ii)
                    c[ii] = __builtin_amdgcn_mfma_f32_16x16x32_f16(a[ii][t], bfr[t], c[ii], 0, 0, 0);

            #pragma unroll
            for (int ii = 0; ii < 4; ++ii)
                #pragma unroll
                for (int r = 0; r < 4; ++r)
                    rmax[ii][r] = fmaxf(rmax[ii][r], c[ii][r]);

            bp += 256;
            mqp += 16;
        }

        #pragma unroll
        for (int ii = 0; ii < 4; ++ii)
            #pragma unroll
            for (int r = 0; r < 4; ++r) {
                float v = rmax[ii][r];
                #pragma unroll
                for (int mk = 1; mk <= 8; mk <<= 1)
                    v = fmaxf(v, __shfl_xor(v, mk));    // reduce over n within quad
                if (n == 0) {
                    int sample = (stile0 + ii) * 16 + quad * 4 + r;
                    atomicMax(&smax[sample], enc_f(v));
                    lmax[ks * N_SAMP + sample] = v;     // split-local max
                }
            }
    }

    // ================= ticket =================
    __shared__ unsigned my_t;
    __threadfence();                 // release this block's smax/lmax writes
    __syncthreads();
    if (tid == 0) my_t = atomicAdd(&sync[0], 1u);
    __syncthreads();
    const unsigned t = my_t;
    const unsigned G = gridDim.x;    // 1024

    if (t < G - 272u) return;        // early finishers: done

    if (t >= G - 16u) {
        // ================= builder: split sp =================
        const int sp = (int)(t - (G - 16u));
        if (tid == 0) {              // wait until ALL blocks ticketed (smax final)
            while (atomicAdd(&sync[0], 0u) < G) __builtin_amdgcn_s_sleep(8);
        }
        __syncthreads();
        __threadfence();             // acquire
        __shared__ int tot;
        if (tid == 0) tot = 0;
        __syncthreads();
        const float* lrow = lmax + (size_t)sp * N_SAMP;
        int* dst = slist + (size_t)sp * N_SAMP;
        for (int c0 = 0; c0 < N_SAMP; c0 += 256) {
            int s = c0 + tid;
            bool pred = lrow[s] >= dec_f(smax[s]) - MARGIN2;
            unsigned long long b = __ballot(pred);
            int wb = 0;
            if (lane == 0) wb = atomicAdd(&tot, __popcll(b));   // LDS atomic
            wb = __shfl(wb, 0);
            if (pred) dst[wb + __popcll(b & ((1ull << lane) - 1))] = s;
        }
        __syncthreads();
        if (tid == 0) {
            scnt[sp] = tot;
            __threadfence();         // release list
            atomicAdd(&sync[1], 1u);
        }
        return;
    }

    // ================= collector =================
    {
        const unsigned cidx = t - (G - 272u);    // [0,256)
        const int sp = (int)(cidx & 15u);
        const int slot = (int)(cidx >> 4);       // [0,16)
        if (tid == 0) {              // wait for all 16 builders
            while (atomicAdd(&sync[1], 0u) < KSPLIT) __builtin_amdgcn_s_sleep(8);
        }
        __syncthreads();
        __threadfence();             // acquire
        const int count = scnt[sp];
        const int kt0 = sp * KT_PER;
        const int* lst = slist + (size_t)sp * N_SAMP;

        for (int tile = slot * 4 + wv; tile * 16 < count; tile += 64) {
            const int base = tile * 16;
            // lane's A-row sample (row n of the tile = list position base+n)
            int sid_n = (base + n < count) ? lst[base + n] : -1;
            // epilogue rows quad*4+r and their thresholds (pad rows never collect)
            int sid_r[4]; float thr[4];
            #pragma unroll
            for (int r = 0; r < 4; ++r) {
                int p = base + quad * 4 + r;
                sid_r[r] = (p < count) ? lst[p] : -1;
                thr[r] = (sid_r[r] >= 0) ? dec_f(smax[sid_r[r]]) - MARGIN2 : FLT_MAX;
            }
            // gathered A-frags: half8 idx = (sid>>4)*256 + (t*4+quad)*16 + (sid&15)
            size_t abase = (sid_n >= 0) ? ((size_t)(sid_n >> 4) * 256 + (sid_n & 15)) : 0;
            half8 a[4];
            #pragma unroll
            for (int tt = 0; tt < 4; ++tt)
                a[tt] = xf[abase + (size_t)(tt * 4 + quad) * 16];

            const half8* bp = mf + (size_t)kt0 * 256 + (quad * 16 + n);
            const float* mqp = msq + kt0 * 16 + n;
            #pragma unroll 1
            for (int kt = 0; kt < KT_PER; ++kt) {
                half8 bfr[4];
                #pragma unroll
                for (int tt = 0; tt < 4; ++tt) bfr[tt] = bp[tt * 64];
                float mq = *mqp;
                floatx4 c = {mq, mq, mq, mq};
                #pragma unroll
                for (int tt = 0; tt < 4; ++tt)
                    c = __builtin_amdgcn_mfma_f32_16x16x32_f16(a[tt], bfr[tt], c, 0, 0, 0);
                #pragma unroll
                for (int r = 0; r < 4; ++r) {
                    if (c[r] >= thr[r]) {
                        int slotc = atomicAdd(&cnt[sid_r[r]], 1);
                        if (slotc < CAP) cand[sid_r[r] * CAP + slotc] = (kt0 + kt) * 16 + n;
                    }
                }
                bp += 256;
                mqp += 16;
            }
        }
    }
}

// ---- Kernel 3: fused exact fp32 rescue + quantize gather + MSE. One wave per sample.
__global__ __launch_bounds__(256) void rescue_quant_kernel(
        const float* __restrict__ x, const float* __restrict__ mT,
        const float* __restrict__ msq, const int* __restrict__ cnt,
        const int* __restrict__ cand, float* __restrict__ qout,
        float* __restrict__ idx_f, float* __restrict__ diff_out) {
    const int wv = threadIdx.x >> 6, lane = threadIdx.x & 63;
    const int s = blockIdx.x * 4 + wv;
    const float2 xx = ((const float2*)x)[(size_t)s * 64 + lane];
    const int c = cnt[s];
    float best = -FLT_MAX; int bk = 0x7fffffff;
    if (c <= CAP) {
        for (int i = 0; i < c; ++i) {
            int k = cand[s * CAP + i];
            float2 mm = ((const float2*)mT)[(size_t)k * 64 + lane];
            float p = xx.x * mm.x + xx.y * mm.y;
            #pragma unroll
            for (int off = 32; off; off >>= 1) p += __shfl_xor(p, off);
            float sc = msq[k] - 2.f * p;
            if (sc > best || (sc == best && k < bk)) { best = sc; bk = k; }
        }
    } else {                                    // overflow: exact full scan (never expected)
        for (int k = 0; k < K_CLUST; ++k) {
            float2 mm = ((const float2*)mT)[(size_t)k * 64 + lane];
            float p = xx.x * mm.x + xx.y * mm.y;
            #pragma unroll
            for (int off = 32; off; off >>= 1) p += __shfl_xor(p, off);
            float sc = msq[k] - 2.f * p;
            if (sc > best) { best = sc; bk = k; }   // ascending k: '>' keeps lowest
        }
    }
    // all lanes hold identical bk (xor-reductions). Gather quantized vector, write, MSE.
    float2 mm = ((const float2*)mT)[(size_t)bk * 64 + lane];
    ((float2*)qout)[(size_t)s * 64 + lane] = mm;
    float dx = xx.x - mm.x, dy = xx.y - mm.y;
    float dd = dx * dx + dy * dy;
    #pragma unroll
    for (int off = 32; off; off >>= 1) dd += __shfl_xor(dd, off);
    __shared__ float wsum[4];
    if (lane == 0) { wsum[wv] = dd; idx_f[s] = (float)bk; }
    __syncthreads();
    if (threadIdx.x == 0)
        atomicAdd(diff_out, (wsum[0] + wsum[1] + wsum[2] + wsum[3])
                              * (1.0f / ((float)N_SAMP * (float)DIM)));
}

extern "C" void kernel_launch(void* const* d_in, const int* in_sizes, int n_in,
                              void* d_out, int out_size, void* d_ws, size_t ws_size,
                              hipStream_t stream) {
    const float* x = (const float*)d_in[0];          // [16,32,32,128]
    const float* m = (const float*)d_in[1];          // [128,10000]
    float* out    = (float*)d_out;
    float* quant  = out;                                  // 2,097,152 f
    float* idx_f  = out + (size_t)N_SAMP * DIM;           // 16,384 f
    float* diff   = out + (size_t)N_SAMP * DIM + N_SAMP;  // 1 f

    char* ws = (char*)d_ws;                  // ~14.3 MB total
    float*     msq  = (float*)    (ws);                       // 10240 f  (40,960 B)
    float*     mT   = (float*)    (ws + 40960);               // 10000*128 f (5,120,000 B)
    _Float16*  mh   = (_Float16*) (ws + 5160960);             // 10240*128 h (2,621,440 B)
    _Float16*  xh   = (_Float16*) (ws + 7782400);             // 16384*128 h (4,194,304 B)
    unsigned*  smax = (unsigned*) (ws + 11976704);            // 16384 u
    int*       cnt  = (int*)      (ws + 12042240);            // 16384 i
    // lmax (written by mbc phase 1, read by builders) overlays cand (written by
    // collectors, read by rescue) — wait, both live inside mbc now: keep SEPARATE.
    float*     lmax = (float*)    (ws + 12107776);            // 16*16384 f (1,048,576 B)
    int*       cand = (int*)      (ws + 13156352);            // 16384*CAP i (1,048,576 B)
    unsigned*  sync = (unsigned*) (ws + 14204928);            // 2 u (pad to 64B)
    int*       scnt  = (int*)     (ws + 14204992);            // 16 i (pad to 64B)
    int*       slist = (int*)     (ws + 14205056);            // 16*16384 i -> ends 15,253,632

    prep_kernel<<<416, 256, 0, stream>>>(m, x, msq, mT, mh, xh, smax, cnt, sync, diff);
    mbc_kernel<<<64 * KSPLIT, 256, 0, stream>>>(xh, mh, msq, smax, lmax, scnt, slist, cnt, cand, sync);
    rescue_quant_kernel<<<N_SAMP / 4, 256, 0, stream>>>(x, mT, msq, cnt, cand, quant, idx_f, diff);
}

// Round 7
// 261.684 us; speedup vs baseline: 1.4142x; 1.4142x over previous
//
#include <hip/hip_runtime.h>
#include <float.h>

#define K_CLUST 10000
#define K_PAD   10240           // 640 k-tiles of 16
#define DIM     128
#define N_SAMP  16384
#define KSPLIT  16
#define KT_PER  40              // 640 ktiles / 16 splits
#define CAP     16              // candidate list capacity per sample
#define MARGIN2 1.5f            // 2x worst-case f16 score error (~0.38) each side
#define NBPS    32              // collect: blocks per split

typedef _Float16 half8  __attribute__((ext_vector_type(8)));
typedef float    floatx4 __attribute__((ext_vector_type(4)));

// order-preserving float<->uint encoding for atomicMax
__device__ inline unsigned enc_f(float f) {
    unsigned u = __float_as_uint(f);
    return u ^ (((int)u >> 31) | 0x80000000u);
}
__device__ inline float dec_f(unsigned u) {
    unsigned t = (u & 0x80000000u) ? (u ^ 0x80000000u) : ~u;
    return __uint_as_float(t);
}

// ---- Kernel 1: prep. blocks [0,160): m-side (msq, mT, mh). [160,416): x-side (xh, inits).
// mh stores (-2 * m) in f16, so the score MFMA computes msq + x·(-2m) directly with
// msq folded into the accumulator init (no fmaf epilogue in the score loop).
__global__ __launch_bounds__(256) void prep_kernel(
        const float* __restrict__ m, const float* __restrict__ x,
        float* __restrict__ msq, float* __restrict__ mT,
        _Float16* __restrict__ mh, _Float16* __restrict__ xh,
        unsigned* __restrict__ smax, int* __restrict__ cnt,
        int* __restrict__ scnt, float* __restrict__ diff_out) {
    __shared__ float tile[64][DIM + 1];
    __shared__ float psum[64][4];
    const int b = blockIdx.x, tid = threadIdx.x;

    if (b < 160) {                              // ---- m part: k0 = b*64
        const int k0 = b * 64;
        const int kl = tid & 63, dg = tid >> 6;
        const int k = k0 + kl;
        float ss = 0.f;
        #pragma unroll 4
        for (int dd = 0; dd < 32; ++dd) {
            int d = dg * 32 + dd;
            float v = (k < K_CLUST) ? m[(size_t)d * K_CLUST + k] : 0.f;
            tile[kl][d] = v;
            ss = fmaf(v, v, ss);
        }
        psum[kl][dg] = ss;
        __syncthreads();
        if (dg == 0)
            msq[k] = (k < K_CLUST) ? (psum[kl][0] + psum[kl][1] + psum[kl][2] + psum[kl][3])
                                   : -1e30f;    // pad never wins
        // mh: [k/16][d/8][k%16][d%8] f16, 16B chunks, scaled by -2
        #pragma unroll
        for (int p = 0; p < 4; ++p) {
            int c = tid + p * 256;              // 0..1023
            int kt = c >> 8, dgc = (c >> 4) & 15, k16 = c & 15;
            half8 hv;
            #pragma unroll
            for (int j = 0; j < 8; ++j)
                hv[j] = (_Float16)(-2.0f * tile[kt * 16 + k16][dgc * 8 + j]);
            size_t ci = ((size_t)(b * 4 + kt) * 16 + dgc) * 16 + k16;
            ((half8*)mh)[ci] = hv;
        }
        // mT [K,DIM] fp32 for rescue/quant gather (unscaled)
        const int r = tid >> 2, p2 = tid & 3;
        if (k0 + r < K_CLUST) {
            float4* dst = (float4*)(mT + (size_t)(k0 + r) * DIM + p2 * 32);
            #pragma unroll
            for (int j = 0; j < 8; ++j) {
                float4 v;
                v.x = tile[r][p2 * 32 + 4 * j + 0];
                v.y = tile[r][p2 * 32 + 4 * j + 1];
                v.z = tile[r][p2 * 32 + 4 * j + 2];
                v.w = tile[r][p2 * 32 + 4 * j + 3];
                dst[j] = v;
            }
        }
    } else {                                    // ---- x part: s0 = (b-160)*64
        const int s0 = (b - 160) * 64;
        const float4* xg = (const float4*)(x + (size_t)s0 * DIM);
        #pragma unroll
        for (int i = 0; i < 8; ++i) {
            int fi = tid + i * 256;             // 0..2047
            int sl = fi >> 5, d4 = fi & 31;
            float4 v = xg[fi];
            tile[sl][d4 * 4 + 0] = v.x; tile[sl][d4 * 4 + 1] = v.y;
            tile[sl][d4 * 4 + 2] = v.z; tile[sl][d4 * 4 + 3] = v.w;
        }
        __syncthreads();
        // xh: [s/16][d/8][s%16][d%8]
        #pragma unroll
        for (int p = 0; p < 4; ++p) {
            int c = tid + p * 256;
            int st = c >> 8, dgc = (c >> 4) & 15, ml = c & 15;
            half8 hv;
            #pragma unroll
            for (int j = 0; j < 8; ++j) hv[j] = (_Float16)tile[st * 16 + ml][dgc * 8 + j];
            size_t ci = ((size_t)(s0 / 16 + st) * 16 + dgc) * 16 + ml;
            ((half8*)xh)[ci] = hv;
        }
        if (tid < 64) { smax[s0 + tid] = 0u; cnt[s0 + tid] = 0; }
        if (b == 160) {
            if (tid < KSPLIT) scnt[tid] = 0;
            if (tid == 0) *diff_out = 0.f;
        }
    }
}

// ---- Kernel 2: f16 MFMA max pass (4 tiles/wave geometry, proven fastest r0-r5).
// Per-sample global max via atomicMax AND per-(sample, split) max to lmax[split][sample]
// (each (sample, split) owned by exactly one wave -> plain store).
__global__ __launch_bounds__(256, 4) void max_kernel(
        const _Float16* __restrict__ xh, const _Float16* __restrict__ mh,
        const float* __restrict__ msq, unsigned* __restrict__ smax,
        float* __restrict__ lmax) {
    const int tid = threadIdx.x;
    const int wv = tid >> 6, lane = tid & 63;
    const int n = lane & 15, quad = lane >> 4;
    const int ks = blockIdx.x & (KSPLIT - 1);
    const int grp = blockIdx.x / KSPLIT;        // [0,64)
    const int stile0 = (grp * 4 + wv) * 4;      // 4 sample-tiles per wave
    const int kt0 = ks * KT_PER;

    const half8* xf = (const half8*)xh;
    const half8* mf = (const half8*)mh;

    half8 a[4][4];
    #pragma unroll
    for (int ii = 0; ii < 4; ++ii)
        #pragma unroll
        for (int t = 0; t < 4; ++t)
            a[ii][t] = xf[((size_t)(stile0 + ii) * 16 + t * 4 + quad) * 16 + n];

    float rmax[4][4];
    #pragma unroll
    for (int ii = 0; ii < 4; ++ii)
        #pragma unroll
        for (int r = 0; r < 4; ++r) rmax[ii][r] = -FLT_MAX;

    const half8* bp = mf + (size_t)kt0 * 256 + (quad * 16 + n);
    const float* mqp = msq + kt0 * 16 + n;

    #pragma unroll 1
    for (int kt = 0; kt < KT_PER; ++kt) {
        half8 bfr[4];
        #pragma unroll
        for (int t = 0; t < 4; ++t) bfr[t] = bp[t * 64];
        float mq = *mqp;

        floatx4 c[4];
        #pragma unroll
        for (int ii = 0; ii < 4; ++ii)
            c[ii] = (floatx4){mq, mq, mq, mq};   // msq folded: col = lane&15 = k-col
        #pragma unroll
        for (int t = 0; t < 4; ++t)
            #pragma unroll
            for (int ii = 0; ii < 4; ++ii)
                c[ii] = __builtin_amdgcn_mfma_f32_16x16x32_f16(a[ii][t], bfr[t], c[ii], 0, 0, 0);

        #pragma unroll
        for (int ii = 0; ii < 4; ++ii)
            #pragma unroll
            for (int r = 0; r < 4; ++r)
                rmax[ii][r] = fmaxf(rmax[ii][r], c[ii][r]);

        bp += 256;
        mqp += 16;
    }

    #pragma unroll
    for (int ii = 0; ii < 4; ++ii)
        #pragma unroll
        for (int r = 0; r < 4; ++r) {
            float v = rmax[ii][r];
            #pragma unroll
            for (int mk = 1; mk <= 8; mk <<= 1)
                v = fmaxf(v, __shfl_xor(v, mk));    // reduce over n within quad
            if (n == 0) {
                int sample = (stile0 + ii) * 16 + quad * 4 + r;
                atomicMax(&smax[sample], enc_f(v));
                lmax[ks * N_SAMP + sample] = v;     // split-local max
            }
        }
}

// ---- Kernel 3: build per-split worklists of samples whose split-local max is
// within MARGIN2 of the global max. 256 blocks = 16 per split (r5's 16-block
// version was latency-bound at ~16 µs). One GLOBAL atomic per wave-ballot chunk:
// 256 blocks x 16 chunks = 4096 atomics over 16 counters — negligible (r4's
// pathology was 262k same-address atomics, not this). List order is irrelevant.
__global__ __launch_bounds__(256) void build_kernel(
        const unsigned* __restrict__ smax, const float* __restrict__ lmax,
        int* __restrict__ scnt, int* __restrict__ slist) {
    const int sp = blockIdx.x & (KSPLIT - 1);
    const int seg = blockIdx.x >> 4;            // [0,16): 1024 samples each
    const int tid = threadIdx.x, lane = tid & 63;
    const float* lrow = lmax + (size_t)sp * N_SAMP;
    int* dst = slist + (size_t)sp * N_SAMP;
    for (int c0 = seg * 1024; c0 < (seg + 1) * 1024; c0 += 256) {
        int s = c0 + tid;
        bool pred = lrow[s] >= dec_f(smax[s]) - MARGIN2;
        unsigned long long b = __ballot(pred);
        int wb = 0;
        if (lane == 0) wb = atomicAdd(&scnt[sp], __popcll(b));
        wb = __shfl(wb, 0);
        if (pred) dst[wb + __popcll(b & ((1ull << lane) - 1))] = s;
    }
}

// ---- Kernel 4: gathered collect. Per split, waves take 16 listed samples per MFMA
// tile (A-rows are per-lane loads -> scattered sample ids are free). Same threshold/
// CAP semantics as the old full collect pass, ~14x less GEMM work on random data.
__global__ __launch_bounds__(256) void collect_kernel(
        const _Float16* __restrict__ xh, const _Float16* __restrict__ mh,
        const float* __restrict__ msq, const unsigned* __restrict__ smax,
        const int* __restrict__ scnt, const int* __restrict__ slist,
        int* __restrict__ cnt, int* __restrict__ cand) {
    const int tid = threadIdx.x;
    const int wv = tid >> 6, lane = tid & 63;
    const int n = lane & 15, quad = lane >> 4;
    const int sp = blockIdx.x / NBPS, bi = blockIdx.x % NBPS;
    const int count = scnt[sp];
    const int kt0 = sp * KT_PER;
    const half8* xf = (const half8*)xh;
    const half8* mf = (const half8*)mh;
    const int* lst = slist + (size_t)sp * N_SAMP;

    for (int base = (bi * 4 + wv) * 16; base < count; base += NBPS * 4 * 16) {
        // lane's A-row sample (row n of the tile = list position base+n)
        int sid_n = (base + n < count) ? lst[base + n] : -1;
        // epilogue rows quad*4+r and their thresholds (pad rows never collect)
        int sid_r[4]; float thr[4];
        #pragma unroll
        for (int r = 0; r < 4; ++r) {
            int p = base + quad * 4 + r;
            sid_r[r] = (p < count) ? lst[p] : -1;
            thr[r] = (sid_r[r] >= 0) ? dec_f(smax[sid_r[r]]) - MARGIN2 : FLT_MAX;
        }
        // gathered A-frags: half8 idx = (sid>>4)*256 + (t*4+quad)*16 + (sid&15)
        size_t abase = (sid_n >= 0) ? ((size_t)(sid_n >> 4) * 256 + (sid_n & 15)) : 0;
        half8 a[4];
        #pragma unroll
        for (int t = 0; t < 4; ++t)
            a[t] = xf[abase + (size_t)(t * 4 + quad) * 16];

        const half8* bp = mf + (size_t)kt0 * 256 + (quad * 16 + n);
        const float* mqp = msq + kt0 * 16 + n;
        #pragma unroll 1
        for (int kt = 0; kt < KT_PER; ++kt) {
            half8 bfr[4];
            #pragma unroll
            for (int t = 0; t < 4; ++t) bfr[t] = bp[t * 64];
            float mq = *mqp;
            floatx4 c = {mq, mq, mq, mq};
            #pragma unroll
            for (int t = 0; t < 4; ++t)
                c = __builtin_amdgcn_mfma_f32_16x16x32_f16(a[t], bfr[t], c, 0, 0, 0);
            #pragma unroll
            for (int r = 0; r < 4; ++r) {
                if (c[r] >= thr[r]) {
                    int slot = atomicAdd(&cnt[sid_r[r]], 1);
                    if (slot < CAP) cand[sid_r[r] * CAP + slot] = (kt0 + kt) * 16 + n;
                }
            }
            bp += 256;
            mqp += 16;
        }
    }
}

// ---- Kernel 5: fused exact fp32 rescue + quantize gather + MSE. One wave per sample.
// (All lanes end the candidate loop with identical (best, bk) since the dot products
// are xor-reduced to every lane.)
__global__ __launch_bounds__(256) void rescue_quant_kernel(
        const float* __restrict__ x, const float* __restrict__ mT,
        const float* __restrict__ msq, const int* __restrict__ cnt,
        const int* __restrict__ cand, float* __restrict__ qout,
        float* __restrict__ idx_f, float* __restrict__ diff_out) {
    const int wv = threadIdx.x >> 6, lane = threadIdx.x & 63;
    const int s = blockIdx.x * 4 + wv;
    const float2 xx = ((const float2*)x)[(size_t)s * 64 + lane];
    const int c = cnt[s];
    float best = -FLT_MAX; int bk = 0x7fffffff;
    if (c <= CAP) {
        for (int i = 0; i < c; ++i) {
            int k = cand[s * CAP + i];
            float2 mm = ((const float2*)mT)[(size_t)k * 64 + lane];
            float p = xx.x * mm.x + xx.y * mm.y;
            #pragma unroll
            for (int off = 32; off; off >>= 1) p += __shfl_xor(p, off);
            float sc = msq[k] - 2.f * p;
            if (sc > best || (sc == best && k < bk)) { best = sc; bk = k; }
        }
    } else {                                    // overflow: exact full scan (never expected)
        for (int k = 0; k < K_CLUST; ++k) {
            float2 mm = ((const float2*)mT)[(size_t)k * 64 + lane];
            float p = xx.x * mm.x + xx.y * mm.y;
            #pragma unroll
            for (int off = 32; off; off >>= 1) p += __shfl_xor(p, off);
            float sc = msq[k] - 2.f * p;
            if (sc > best) { best = sc; bk = k; }   // ascending k: '>' keeps lowest
        }
    }
    float2 mm = ((const float2*)mT)[(size_t)bk * 64 + lane];
    ((float2*)qout)[(size_t)s * 64 + lane] = mm;
    float dx = xx.x - mm.x, dy = xx.y - mm.y;
    float dd = dx * dx + dy * dy;
    #pragma unroll
    for (int off = 32; off; off >>= 1) dd += __shfl_xor(dd, off);
    __shared__ float wsum[4];
    if (lane == 0) { wsum[wv] = dd; idx_f[s] = (float)bk; }
    __syncthreads();
    if (threadIdx.x == 0)
        atomicAdd(diff_out, (wsum[0] + wsum[1] + wsum[2] + wsum[3])
                              * (1.0f / ((float)N_SAMP * (float)DIM)));
}

extern "C" void kernel_launch(void* const* d_in, const int* in_sizes, int n_in,
                              void* d_out, int out_size, void* d_ws, size_t ws_size,
                              hipStream_t stream) {
    const float* x = (const float*)d_in[0];          // [16,32,32,128]
    const float* m = (const float*)d_in[1];          // [128,10000]
    float* out    = (float*)d_out;
    float* quant  = out;                                  // 2,097,152 f
    float* idx_f  = out + (size_t)N_SAMP * DIM;           // 16,384 f
    float* diff   = out + (size_t)N_SAMP * DIM + N_SAMP;  // 1 f

    char* ws = (char*)d_ws;                  // ~14.2 MB total
    float*     msq  = (float*)    (ws);                       // 10240 f  (40,960 B)
    float*     mT   = (float*)    (ws + 40960);               // 10000*128 f (5,120,000 B)
    _Float16*  mh   = (_Float16*) (ws + 5160960);             // 10240*128 h (2,621,440 B)
    _Float16*  xh   = (_Float16*) (ws + 7782400);             // 16384*128 h (4,194,304 B)
    unsigned*  smax = (unsigned*) (ws + 11976704);            // 16384 u
    int*       cnt  = (int*)      (ws + 12042240);            // 16384 i
    // lmax (written by max_kernel, read by build) overlays cand (written by collect,
    // read by rescue) — live ranges are disjoint, both exactly 1,048,576 B.
    float*     lmax = (float*)    (ws + 12107776);            // 16*16384 f
    int*       cand = (int*)      (ws + 12107776);            // 16384*CAP i
    int*       scnt  = (int*)     (ws + 13156352);            // 16 i (pad to 64B)
    int*       slist = (int*)     (ws + 13156416);            // 16*16384 i -> ends 14,204,992

    prep_kernel<<<416, 256, 0, stream>>>(m, x, msq, mT, mh, xh, smax, cnt, scnt, diff);
    max_kernel<<<64 * KSPLIT, 256, 0, stream>>>(xh, mh, msq, smax, lmax);
    build_kernel<<<256, 256, 0, stream>>>(smax, lmax, scnt, slist);
    collect_kernel<<<KSPLIT * NBPS, 256, 0, stream>>>(xh, mh, msq, smax, scnt, slist, cnt, cand);
    rescue_quant_kernel<<<N_SAMP / 4, 256, 0, stream>>>(x, mT, msq, cnt, cand, quant, idx_f, diff);
}

// Round 8
// 214.461 us; speedup vs baseline: 1.7256x; 1.2202x over previous
//
#include <hip/hip_runtime.h>
#include <float.h>

#define K_CLUST 10000
#define K_PAD   10240           // 640 k-tiles of 16
#define DIM     128
#define N_SAMP  16384
#define KSPLIT  16
#define KT_PER  40              // 640 ktiles / 16 splits
#define CAP     16              // candidate list capacity per sample
#define MARGIN2 1.5f            // 2x worst-case f16 score error (~0.38) each side

typedef _Float16 half8  __attribute__((ext_vector_type(8)));
typedef float    floatx4 __attribute__((ext_vector_type(4)));

// order-preserving float<->uint encoding for atomicMax
__device__ inline unsigned enc_f(float f) {
    unsigned u = __float_as_uint(f);
    return u ^ (((int)u >> 31) | 0x80000000u);
}
__device__ inline float dec_f(unsigned u) {
    unsigned t = (u & 0x80000000u) ? (u ^ 0x80000000u) : ~u;
    return __uint_as_float(t);
}

// ---- Kernel 1: prep. blocks [0,160): m-side (msq, mT, mh). [160,416): x-side (xh, inits).
// mh stores (-2 * m) in f16 (exact power-of-2 scale), so the score MFMA computes
// msq + x·(-2m) directly with msq folded into the accumulator init — no fmaf epilogue.
__global__ __launch_bounds__(256) void prep_kernel(
        const float* __restrict__ m, const float* __restrict__ x,
        float* __restrict__ msq, float* __restrict__ mT,
        _Float16* __restrict__ mh, _Float16* __restrict__ xh,
        unsigned* __restrict__ smax, int* __restrict__ cnt,
        float* __restrict__ diff_out) {
    __shared__ float tile[64][DIM + 1];
    __shared__ float psum[64][4];
    const int b = blockIdx.x, tid = threadIdx.x;

    if (b < 160) {                              // ---- m part: k0 = b*64
        const int k0 = b * 64;
        const int kl = tid & 63, dg = tid >> 6;
        const int k = k0 + kl;
        float ss = 0.f;
        #pragma unroll 4
        for (int dd = 0; dd < 32; ++dd) {
            int d = dg * 32 + dd;
            float v = (k < K_CLUST) ? m[(size_t)d * K_CLUST + k] : 0.f;
            tile[kl][d] = v;
            ss = fmaf(v, v, ss);
        }
        psum[kl][dg] = ss;
        __syncthreads();
        if (dg == 0)
            msq[k] = (k < K_CLUST) ? (psum[kl][0] + psum[kl][1] + psum[kl][2] + psum[kl][3])
                                   : -1e30f;    // pad never wins
        // mh: [k/16][d/8][k%16][d%8] f16, 16B chunks, scaled by -2
        #pragma unroll
        for (int p = 0; p < 4; ++p) {
            int c = tid + p * 256;              // 0..1023
            int kt = c >> 8, dgc = (c >> 4) & 15, k16 = c & 15;
            half8 hv;
            #pragma unroll
            for (int j = 0; j < 8; ++j)
                hv[j] = (_Float16)(-2.0f * tile[kt * 16 + k16][dgc * 8 + j]);
            size_t ci = ((size_t)(b * 4 + kt) * 16 + dgc) * 16 + k16;
            ((half8*)mh)[ci] = hv;
        }
        // mT [K,DIM] fp32 for rescue/quant gather (unscaled)
        const int r = tid >> 2, p2 = tid & 3;
        if (k0 + r < K_CLUST) {
            float4* dst = (float4*)(mT + (size_t)(k0 + r) * DIM + p2 * 32);
            #pragma unroll
            for (int j = 0; j < 8; ++j) {
                float4 v;
                v.x = tile[r][p2 * 32 + 4 * j + 0];
                v.y = tile[r][p2 * 32 + 4 * j + 1];
                v.z = tile[r][p2 * 32 + 4 * j + 2];
                v.w = tile[r][p2 * 32 + 4 * j + 3];
                dst[j] = v;
            }
        }
    } else {                                    // ---- x part: s0 = (b-160)*64
        const int s0 = (b - 160) * 64;
        const float4* xg = (const float4*)(x + (size_t)s0 * DIM);
        #pragma unroll
        for (int i = 0; i < 8; ++i) {
            int fi = tid + i * 256;             // 0..2047
            int sl = fi >> 5, d4 = fi & 31;
            float4 v = xg[fi];
            tile[sl][d4 * 4 + 0] = v.x; tile[sl][d4 * 4 + 1] = v.y;
            tile[sl][d4 * 4 + 2] = v.z; tile[sl][d4 * 4 + 3] = v.w;
        }
        __syncthreads();
        // xh: [s/16][d/8][s%16][d%8]
        #pragma unroll
        for (int p = 0; p < 4; ++p) {
            int c = tid + p * 256;
            int st = c >> 8, dgc = (c >> 4) & 15, ml = c & 15;
            half8 hv;
            #pragma unroll
            for (int j = 0; j < 8; ++j) hv[j] = (_Float16)tile[st * 16 + ml][dgc * 8 + j];
            size_t ci = ((size_t)(s0 / 16 + st) * 16 + dgc) * 16 + ml;
            ((half8*)xh)[ci] = hv;
        }
        if (tid < 64) { smax[s0 + tid] = 0u; cnt[s0 + tid] = 0; }
        if (b == 160 && tid == 0) *diff_out = 0.f;
    }
}

// ---- Kernel 2/3: f16 MFMA score pass (r0 geometry: 4 tiles/wave, no prefetch —
// the only structure that hit 59 µs; msq-fold verified to take it to 54 µs as
// max_kernel in r5-r7). COLLECT=false: per-sample max (atomicMax). COLLECT=true:
// gather candidates with score >= max - MARGIN2.
template <bool COLLECT>
__global__ __launch_bounds__(256, 4) void score_kernel(
        const _Float16* __restrict__ xh, const _Float16* __restrict__ mh,
        const float* __restrict__ msq, unsigned* __restrict__ smax,
        int* __restrict__ cnt, int* __restrict__ cand) {
    const int tid = threadIdx.x;
    const int wv = tid >> 6, lane = tid & 63;
    const int n = lane & 15, quad = lane >> 4;
    const int ks = blockIdx.x & (KSPLIT - 1);
    const int grp = blockIdx.x / KSPLIT;        // [0,64)
    const int stile0 = (grp * 4 + wv) * 4;      // 4 sample-tiles per wave
    const int kt0 = ks * KT_PER;

    const half8* xf = (const half8*)xh;
    const half8* mf = (const half8*)mh;

    // A-frags resident across the whole k-loop: 16 x half8 = 64 VGPRs
    half8 a[4][4];
    #pragma unroll
    for (int ii = 0; ii < 4; ++ii)
        #pragma unroll
        for (int t = 0; t < 4; ++t)
            a[ii][t] = xf[((size_t)(stile0 + ii) * 16 + t * 4 + quad) * 16 + n];

    float rmax[4][4];
    float thr[4][4];
    #pragma unroll
    for (int ii = 0; ii < 4; ++ii)
        #pragma unroll
        for (int r = 0; r < 4; ++r) {
            rmax[ii][r] = -FLT_MAX;
            if (COLLECT)
                thr[ii][r] = dec_f(smax[(stile0 + ii) * 16 + quad * 4 + r]) - MARGIN2;
        }

    // B pointer: linear half8 index = kt*256 + t*64 + quad*16 + n
    const half8* bp = mf + (size_t)kt0 * 256 + (quad * 16 + n);
    const float* mqp = msq + kt0 * 16 + n;

    #pragma unroll 1
    for (int kt = 0; kt < KT_PER; ++kt) {
        half8 bfr[4];
        #pragma unroll
        for (int t = 0; t < 4; ++t) bfr[t] = bp[t * 64];
        float mq = *mqp;

        floatx4 c[4];
        #pragma unroll
        for (int ii = 0; ii < 4; ++ii)
            c[ii] = (floatx4){mq, mq, mq, mq};   // msq folded: col = lane&15 = k-col
        #pragma unroll
        for (int t = 0; t < 4; ++t)
            #pragma unroll
            for (int ii = 0; ii < 4; ++ii)
                c[ii] = __builtin_amdgcn_mfma_f32_16x16x32_f16(a[ii][t], bfr[t], c[ii], 0, 0, 0);

        #pragma unroll
        for (int ii = 0; ii < 4; ++ii)
            #pragma unroll
            for (int r = 0; r < 4; ++r) {
                float sc = c[ii][r];             // score = msq + x·(-2m)
                if (!COLLECT) {
                    rmax[ii][r] = fmaxf(rmax[ii][r], sc);
                } else if (sc >= thr[ii][r]) {
                    int sample = (stile0 + ii) * 16 + quad * 4 + r;
                    int slot = atomicAdd(&cnt[sample], 1);
                    if (slot < CAP) cand[sample * CAP + slot] = (kt0 + kt) * 16 + n;
                }
            }

        bp += 256;
        mqp += 16;
    }

    if (!COLLECT) {
        #pragma unroll
        for (int ii = 0; ii < 4; ++ii)
            #pragma unroll
            for (int r = 0; r < 4; ++r) {
                float v = rmax[ii][r];
                #pragma unroll
                for (int mk = 1; mk <= 8; mk <<= 1)
                    v = fmaxf(v, __shfl_xor(v, mk));    // reduce over n within quad
                if (n == 0)
                    atomicMax(&smax[(stile0 + ii) * 16 + quad * 4 + r], enc_f(v));
            }
    }
}

// ---- Kernel 4: exact fp32 rescue over candidates; one wave per sample.
__global__ __launch_bounds__(256) void rescue_kernel(
        const float* __restrict__ x, const float* __restrict__ mT,
        const float* __restrict__ msq, const int* __restrict__ cnt,
        const int* __restrict__ cand, int* __restrict__ idx_i,
        float* __restrict__ idx_f) {
    const int wv = threadIdx.x >> 6, lane = threadIdx.x & 63;
    const int s = blockIdx.x * 4 + wv;
    const float2 xx = ((const float2*)x)[(size_t)s * 64 + lane];
    const int c = cnt[s];
    float best = -FLT_MAX; int bk = 0x7fffffff;
    if (c <= CAP) {
        for (int i = 0; i < c; ++i) {
            int k = cand[s * CAP + i];
            float2 mm = ((const float2*)mT)[(size_t)k * 64 + lane];
            float p = xx.x * mm.x + xx.y * mm.y;
            #pragma unroll
            for (int off = 32; off; off >>= 1) p += __shfl_xor(p, off);
            float sc = msq[k] - 2.f * p;
            if (sc > best || (sc == best && k < bk)) { best = sc; bk = k; }
        }
    } else {                                    // overflow: exact full scan (never expected)
        for (int k = 0; k < K_CLUST; ++k) {
            float2 mm = ((const float2*)mT)[(size_t)k * 64 + lane];
            float p = xx.x * mm.x + xx.y * mm.y;
            #pragma unroll
            for (int off = 32; off; off >>= 1) p += __shfl_xor(p, off);
            float sc = msq[k] - 2.f * p;
            if (sc > best) { best = sc; bk = k; }   // ascending k: '>' keeps lowest
        }
    }
    if (lane == 0) { idx_i[s] = bk; idx_f[s] = (float)bk; }
}

// ---- Kernel 5: gather quantize (coalesced via mT), MSE.
__global__ void quant_kernel(const float* __restrict__ x, const float* __restrict__ mT,
                             const int* __restrict__ idx_i, float* __restrict__ qout,
                             float* __restrict__ diff_out) {
    int g = blockIdx.x * 256 + threadIdx.x;     // one thread per (sample, d4)
    int samp = g >> 5;
    int d4   = g & 31;
    int idx  = idx_i[samp];
    float4 q  = ((const float4*)mT)[(size_t)idx * (DIM / 4) + d4];
    float4 xv = ((const float4*)x)[g];
    ((float4*)qout)[g] = q;
    float ax = xv.x - q.x, ay = xv.y - q.y, az = xv.z - q.z, aw = xv.w - q.w;
    float dd = ax * ax + ay * ay + az * az + aw * aw;
    #pragma unroll
    for (int off = 32; off; off >>= 1) dd += __shfl_down(dd, off);
    __shared__ float wsum[4];
    int lane = threadIdx.x & 63, wv = threadIdx.x >> 6;
    if (lane == 0) wsum[wv] = dd;
    __syncthreads();
    if (threadIdx.x == 0) {
        float t = wsum[0] + wsum[1] + wsum[2] + wsum[3];
        atomicAdd(diff_out, t * (1.0f / ((float)N_SAMP * (float)DIM)));
    }
}

extern "C" void kernel_launch(void* const* d_in, const int* in_sizes, int n_in,
                              void* d_out, int out_size, void* d_ws, size_t ws_size,
                              hipStream_t stream) {
    const float* x = (const float*)d_in[0];          // [16,32,32,128]
    const float* m = (const float*)d_in[1];          // [128,10000]
    float* out    = (float*)d_out;
    float* quant  = out;                                  // 2,097,152 f
    float* idx_f  = out + (size_t)N_SAMP * DIM;           // 16,384 f
    float* diff   = out + (size_t)N_SAMP * DIM + N_SAMP;  // 1 f

    char* ws = (char*)d_ws;                  // ~13.2 MB total
    float*     msq  = (float*)    (ws);                       // 10240 f  (40,960 B)
    float*     mT   = (float*)    (ws + 40960);               // 10000*128 f (5,120,000 B)
    _Float16*  mh   = (_Float16*) (ws + 5160960);             // 10240*128 h (2,621,440 B)
    _Float16*  xh   = (_Float16*) (ws + 7782400);             // 16384*128 h (4,194,304 B)
    unsigned*  smax = (unsigned*) (ws + 11976704);            // 16384 u
    int*       cnt  = (int*)      (ws + 12042240);            // 16384 i
    int*       cand = (int*)      (ws + 12107776);            // 16384*CAP i (1,048,576 B)
    int*       idx_i = (int*)(ws + 13156352);                 // 16384 i

    prep_kernel<<<416, 256, 0, stream>>>(m, x, msq, mT, mh, xh, smax, cnt, diff);
    score_kernel<false><<<64 * KSPLIT, 256, 0, stream>>>(xh, mh, msq, smax, cnt, cand);
    score_kernel<true><<<64 * KSPLIT, 256, 0, stream>>>(xh, mh, msq, smax, cnt, cand);
    rescue_kernel<<<N_SAMP / 4, 256, 0, stream>>>(x, mT, msq, cnt, cand, idx_i, idx_f);
    quant_kernel<<<(N_SAMP * DIM / 4) / 256, 256, 0, stream>>>(x, mT, idx_i, quant, diff);
}